// Round 1
// baseline (185.941 us; speedup 1.0000x reference)
//
#include <hip/hip_runtime.h>

typedef __attribute__((ext_vector_type(8))) short short8;
typedef __attribute__((ext_vector_type(4))) float f32x4;
typedef unsigned short u16;
typedef unsigned int u32;

#define XH 114
#define XW 114
#define CIN 64
#define COUT 128
#define OH 112
#define OW 112
#define NB 32
#define KTOT 576   // CIN*9
#define BK 32
#define NSTEP 18   // KTOT/BK
#define LDB 40     // padded k-stride (bf16 elems) for B^T tile

static __device__ __forceinline__ u16 f2bf(float f) {
    u32 x = __float_as_uint(f);
    // round-to-nearest-even bf16 (inputs are finite normals)
    u32 r = (x + 0x7fffu + ((x >> 16) & 1u)) >> 16;
    return (u16)r;
}

__global__ __launch_bounds__(256) void wcvt_kernel(const float* __restrict__ w,
                                                   u16* __restrict__ wbf) {
    int i = blockIdx.x * 256 + threadIdx.x;
    if (i < COUT * KTOT) wbf[i] = f2bf(w[i]);
}

__global__ __launch_bounds__(256) void conv_mfma(const float* __restrict__ x,
                                                 const u16* __restrict__ wbf,
                                                 const float* __restrict__ bias,
                                                 float* __restrict__ out) {
    __shared__ u16 ldsB[OW * LDB];   // 112*40*2 = 8960 B

    const int tid = threadIdx.x;
    int bid = blockIdx.x;
    // bijective XCD-aware swizzle: nwg = 3584 = 8 * 448
    {
        int xcd = bid & 7;
        int local = bid >> 3;
        bid = xcd * 448 + local;
    }
    const int b = bid / OH;
    const int h = bid - b * OH;

    const float* xb = x + b * (CIN * XH * XW);
    float* outb = out + b * (COUT * OH * OW) + h * OW;

    const int lane = tid & 63;
    const int wv   = tid >> 6;
    const int l16  = lane & 15;
    const int lhi  = lane >> 4;
    const int m0   = wv * 32;            // wave's cout base (2 M-frags)

    // staging map: 8 threads per k-row, 14 n each
    const int sk  = tid >> 3;            // 0..31
    const int sn0 = (tid & 7) * 14;      // 0,14,...,98

    f32x4 acc[2][7];
    const f32x4 zero = {0.f, 0.f, 0.f, 0.f};
    #pragma unroll
    for (int i = 0; i < 2; ++i)
        #pragma unroll
        for (int j = 0; j < 7; ++j) acc[i][j] = zero;

    for (int t = 0; t < NSTEP; ++t) {
        // ---- decode this thread's k-row (once per K-step) ----
        const int kg = t * BK + sk;          // global k, 0..575
        const int ci = kg / 9;
        const int r9 = kg - ci * 9;
        const int kh = r9 / 3;
        const int kw = r9 - kh * 3;
        const float* src = xb + (ci * XH + (h + kh)) * XW + kw + sn0;

        __syncthreads();   // prev iteration's frag reads done before overwrite
        #pragma unroll
        for (int i = 0; i < 14; ++i) {
            ldsB[(sn0 + i) * LDB + sk] = f2bf(src[i]);
        }
        __syncthreads();

        // ---- A frags straight from global (L2-resident 144 KB) ----
        short8 afrag[2];
        #pragma unroll
        for (int mf = 0; mf < 2; ++mf) {
            const u16* ap = wbf + (m0 + mf * 16 + l16) * KTOT + t * BK + lhi * 8;
            afrag[mf] = *(const short8*)ap;
        }

        // ---- B frags from LDS + MFMA ----
        #pragma unroll
        for (int nf = 0; nf < 7; ++nf) {
            short8 bfrag = *(const short8*)&ldsB[(nf * 16 + l16) * LDB + lhi * 8];
            acc[0][nf] = __builtin_amdgcn_mfma_f32_16x16x32_bf16(afrag[0], bfrag, acc[0][nf], 0, 0, 0);
            acc[1][nf] = __builtin_amdgcn_mfma_f32_16x16x32_bf16(afrag[1], bfrag, acc[1][nf], 0, 0, 0);
        }
    }

    // ---- epilogue: C/D layout col=lane&15, row=(lane>>4)*4+j ----
    #pragma unroll
    for (int mf = 0; mf < 2; ++mf) {
        #pragma unroll
        for (int j = 0; j < 4; ++j) {
            const int o = m0 + mf * 16 + lhi * 4 + j;
            const float bv = bias[o];
            #pragma unroll
            for (int nf = 0; nf < 7; ++nf) {
                outb[o * (OH * OW) + nf * 16 + l16] = acc[mf][nf][j] + bv;
            }
        }
    }
}

extern "C" void kernel_launch(void* const* d_in, const int* in_sizes, int n_in,
                              void* d_out, int out_size, void* d_ws, size_t ws_size,
                              hipStream_t stream) {
    const float* x    = (const float*)d_in[0];
    const float* w    = (const float*)d_in[3];
    const float* bias = (const float*)d_in[4];
    u16* wbf = (u16*)d_ws;   // 73728 * 2 B = 147456 B of scratch

    wcvt_kernel<<<(COUT * KTOT + 255) / 256, 256, 0, stream>>>(w, wbf);
    conv_mfma<<<NB * OH, 256, 0, stream>>>(x, wbf, bias, (float*)d_out);
}